// Round 2
// baseline (341.413 us; speedup 1.0000x reference)
//
#include <hip/hip_runtime.h>
#include <hip/hip_bf16.h>

#define CM 256
#define CZ 128
#define CH 32
#define SS 128
#define NN 384

typedef short bf16x8 __attribute__((ext_vector_type(8)));
typedef float f32x4 __attribute__((ext_vector_type(4)));
typedef unsigned short us4 __attribute__((ext_vector_type(4)));
typedef unsigned short us8 __attribute__((ext_vector_type(8)));

__device__ __forceinline__ unsigned short f2bf(float f) {
    __hip_bfloat16 h = __float2bfloat16(f);
    return __builtin_bit_cast(unsigned short, h);
}

// ---------------- K0: WoT[n][k] = bf16(Wo[k][n]) ----------------
__global__ void k0_wo_t(const float* __restrict__ Wo, unsigned short* __restrict__ WoT) {
    int n = blockIdx.x;  // 0..127
    for (int k = threadIdx.x; k < CH * CH; k += blockDim.x) {
        WoT[n * (CH * CH) + k] = f2bf(Wo[(size_t)k * CZ + n]);
    }
}

// ---------------- K1: LayerNorm + projections (block per i, full S) ----------------
// Lt[(i*32+c)][s] = (LN(msa) @ Wl + bl)[s,i,c] / 128 ; Rt[(i*32+d)][s] = (... @ Wr + br)
#define K1_A_OFF 0
#define K1_B_OFF 67584            // 128*264*2
#define K1_LDS   101376           // + 64*264*2

__global__ __launch_bounds__(512) void k1_ln_proj(
    const float* __restrict__ msa, const float* __restrict__ g, const float* __restrict__ bta,
    const float* __restrict__ Wl, const float* __restrict__ bl,
    const float* __restrict__ Wr, const float* __restrict__ br,
    unsigned short* __restrict__ Lt, unsigned short* __restrict__ Rt)
{
    extern __shared__ char smem[];
    unsigned short* A_lds = (unsigned short*)(smem + K1_A_OFF);  // [128 s][264]
    unsigned short* B_lds = (unsigned short*)(smem + K1_B_OFF);  // [64 n][264]

    const int i    = blockIdx.x;
    const int t    = threadIdx.x;
    const int wv   = t >> 6;
    const int lane = t & 63;
    const int lr   = lane & 15, lg = lane >> 4;

    // --- LN: wave w handles s = w*16 .. +16, lane covers 4 consecutive channels ---
    const float4 gv = ((const float4*)g)[lane];
    const float4 bv = ((const float4*)bta)[lane];
#pragma unroll 4
    for (int r = 0; r < 16; r++) {
        int s = wv * 16 + r;
        float4 v = ((const float4*)(msa + ((size_t)s * NN + i) * CM))[lane];
        float sum = v.x + v.y + v.z + v.w;
        float sq  = v.x * v.x + v.y * v.y + v.z * v.z + v.w * v.w;
#pragma unroll
        for (int off = 32; off >= 1; off >>= 1) {
            sum += __shfl_xor(sum, off, 64);
            sq  += __shfl_xor(sq, off, 64);
        }
        float mu = sum * (1.f / CM);
        float rs = rsqrtf(sq * (1.f / CM) - mu * mu + 1e-5f);
        us4 pk;
        pk[0] = f2bf((v.x - mu) * rs * gv.x + bv.x);
        pk[1] = f2bf((v.y - mu) * rs * gv.y + bv.y);
        pk[2] = f2bf((v.z - mu) * rs * gv.z + bv.z);
        pk[3] = f2bf((v.w - mu) * rs * gv.w + bv.w);
        *(us4*)&A_lds[s * 264 + lane * 4] = pk;
    }
    // --- W staging: B_lds[ch][k] (left), B_lds[32+ch][k] (right) ---
#pragma unroll 4
    for (int u = 0; u < 16; u++) {
        int e = u * 512 + t;          // e < 8192
        int ch = e & 31, k = e >> 5;
        B_lds[ch * 264 + k]        = f2bf(Wl[e]);
        B_lds[(32 + ch) * 264 + k] = f2bf(Wr[e]);
    }
    __syncthreads();

    // --- MFMA: M=128(s) x N=64 x K=256; wave tile 32x32 ---
    const int m0 = (wv >> 1) * 32;
    const int n0 = (wv & 1) * 32;
    f32x4 acc[2][2];
#pragma unroll
    for (int a = 0; a < 2; a++)
#pragma unroll
        for (int b = 0; b < 2; b++) acc[a][b] = (f32x4){0.f, 0.f, 0.f, 0.f};

#pragma unroll
    for (int ks = 0; ks < 8; ks++) {
        int ko = ks * 32 + lg * 8;
        bf16x8 a0 = *(const bf16x8*)&A_lds[(m0 + lr) * 264 + ko];
        bf16x8 a1 = *(const bf16x8*)&A_lds[(m0 + 16 + lr) * 264 + ko];
        bf16x8 b0 = *(const bf16x8*)&B_lds[(n0 + lr) * 264 + ko];
        bf16x8 b1 = *(const bf16x8*)&B_lds[(n0 + 16 + lr) * 264 + ko];
        acc[0][0] = __builtin_amdgcn_mfma_f32_16x16x32_bf16(a0, b0, acc[0][0], 0, 0, 0);
        acc[0][1] = __builtin_amdgcn_mfma_f32_16x16x32_bf16(a0, b1, acc[0][1], 0, 0, 0);
        acc[1][0] = __builtin_amdgcn_mfma_f32_16x16x32_bf16(a1, b0, acc[1][0], 0, 0, 0);
        acc[1][1] = __builtin_amdgcn_mfma_f32_16x16x32_bf16(a1, b1, acc[1][1], 0, 0, 0);
    }

    // --- epilogue: C[m=s][n=ch] -> (Lt|Rt)[(i*32+ch)][s] ---
    const bool isL = (n0 == 0);   // wave-uniform
    const float scale = isL ? 0.0078125f : 1.f;   // 1/128 folded into left
#pragma unroll
    for (int mt = 0; mt < 2; mt++)
#pragma unroll
        for (int nt = 0; nt < 2; nt++) {
            int ch = (n0 + nt * 16 + lr) & 31;
            float bias = isL ? bl[ch] : br[ch];
            us4 pk;
#pragma unroll
            for (int rg = 0; rg < 4; rg++)
                pk[rg] = f2bf((acc[mt][nt][rg] + bias) * scale);
            unsigned short* dst = (isL ? Lt : Rt) + (size_t)(i * CH + ch) * SS + m0 + mt * 16 + lg * 4;
            *(us4*)dst = pk;
        }
}

// ---------------- K2: fused GEMM1 (outer) + GEMM2 (@Wo) ----------------
#define TI 8
#define TJ 8
#define P1_B_OFF 69632     // 256*136*2
#define K2_LDS   139264    // phase1: 2*69632; phase2: O 65536 + 2*32768; reduce: 4*128*68*4
#define WO_OFF   65536

__global__ __launch_bounds__(512, 2) void k2_fused(
    const unsigned short* __restrict__ Lt, const unsigned short* __restrict__ Rt,
    const unsigned short* __restrict__ WoT, const float* __restrict__ bo,
    float* __restrict__ out)
{
    extern __shared__ char smem[];
    unsigned short* A = (unsigned short*)(smem);             // [256][136]
    unsigned short* B = (unsigned short*)(smem + P1_B_OFF);  // [256][136]

    const int i0 = blockIdx.x * TI;
    const int j0 = blockIdx.y * TJ;
    const int t  = threadIdx.x;
    const int wv = t >> 6, lane = t & 63;
    const int lr = lane & 15, lg = lane >> 4;

    // ---- Phase 1 staging ----
    const unsigned short* gA = Lt + (size_t)i0 * CH * SS;
    const unsigned short* gB = Rt + (size_t)j0 * CH * SS;
#pragma unroll
    for (int it = 0; it < 8; it++) {
        int c  = it * 512 + t;
        int rw = c >> 4, kc = c & 15;
        *(us8*)(A + rw * 136 + kc * 8) = *(const us8*)(gA + rw * 128 + kc * 8);
        *(us8*)(B + rw * 136 + kc * 8) = *(const us8*)(gB + rw * 128 + kc * 8);
    }
    __syncthreads();

    // ---- Phase 1 compute: 256x256x128, wave tile 128x64 ----
    const int m0 = (wv >> 2) * 128;
    const int n0w = (wv & 3) * 64;

    f32x4 accE[4][4], accO[4][4];   // even/odd mt split for register lifetime
#pragma unroll
    for (int a = 0; a < 4; a++)
#pragma unroll
        for (int b = 0; b < 4; b++) {
            accE[a][b] = (f32x4){0.f, 0.f, 0.f, 0.f};
            accO[a][b] = (f32x4){0.f, 0.f, 0.f, 0.f};
        }

#pragma unroll
    for (int ks = 0; ks < 4; ks++) {
        int ko = ks * 32 + lg * 8;
        bf16x8 af[8], bfr[4];
#pragma unroll
        for (int mt = 0; mt < 8; mt++) af[mt]  = *(const bf16x8*)(A + (m0 + mt * 16 + lr) * 136 + ko);
#pragma unroll
        for (int nt = 0; nt < 4; nt++) bfr[nt] = *(const bf16x8*)(B + (n0w + nt * 16 + lr) * 136 + ko);
#pragma unroll
        for (int mt = 0; mt < 8; mt++)
#pragma unroll
            for (int nt = 0; nt < 4; nt++) {
                if (mt & 1)
                    accO[mt >> 1][nt] = __builtin_amdgcn_mfma_f32_16x16x32_bf16(af[mt], bfr[nt], accO[mt >> 1][nt], 0, 0, 0);
                else
                    accE[mt >> 1][nt] = __builtin_amdgcn_mfma_f32_16x16x32_bf16(af[mt], bfr[nt], accE[mt >> 1][nt], 0, 0, 0);
            }
    }
    __syncthreads();   // A/B reads complete; LDS repurposed

    // ---- Phase 2: out[pair=64][z=128] = O[64][1024] @ WoT^T, K-split 4 ----
    unsigned short* Oh = (unsigned short*)smem;        // [128 rowH][256] XOR-swizzled
    const int zsl = wv & 1, ksl = wv >> 1;             // z-slot (64), k-slot (4)

    f32x4 acc2[4][4];
#pragma unroll
    for (int a = 0; a < 4; a++)
#pragma unroll
        for (int b = 0; b < 4; b++) acc2[a][b] = (f32x4){0.f, 0.f, 0.f, 0.f};

    for (int h = 0; h < 2; h++) {
        // dump O-half h: acc entries with (mt&1)==h -> c = h*16 + (lg*4+rg)
#pragma unroll
        for (int mh = 0; mh < 4; mh++) {
            int iiw = (wv >> 2) * 4 + mh;              // rowH block
#pragma unroll
            for (int nt = 0; nt < 4; nt++)
#pragma unroll
                for (int rg = 0; rg < 4; rg++) {
                    int rowH = iiw * 16 + lg * 4 + rg;
                    int col  = n0w + nt * 16 + lr;
                    int okey = ((rowH >> 5) ^ (rowH >> 2)) & 7;
                    int chk  = (col >> 3) ^ okey;
                    float v  = h ? accO[mh][nt][rg] : accE[mh][nt][rg];
                    Oh[rowH * 256 + chk * 8 + (col & 7)] = f2bf(v);
                }
        }
        // stage Wo chunk 0 of this half (plain load + swizzled ds_write)
        {
            unsigned short* WD = (unsigned short*)(smem + WO_OFF);   // buf 0
            int kb = h * 512;
#pragma unroll
            for (int q = 0; q < 4; q++) {
                int lam = q * 512 + t;
                int z = lam >> 4, cc = lam & 15;
                int cg = cc ^ (z & 15);
                *(us8*)&WD[lam * 8] = *(const us8*)&WoT[(size_t)z * 1024 + kb + cg * 8];
            }
        }
        __syncthreads();

        for (int cnk = 0; cnk < 4; cnk++) {
            // prefetch next chunk into regs
            us8 wreg[4];
            if (cnk < 3) {
                int kb = h * 512 + (cnk + 1) * 128;
#pragma unroll
                for (int q = 0; q < 4; q++) {
                    int lam = q * 512 + t;
                    int z = lam >> 4, cc = lam & 15;
                    int cg = cc ^ (z & 15);
                    wreg[q] = *(const us8*)&WoT[(size_t)z * 1024 + kb + cg * 8];
                }
            }
            // consume chunk cnk from buf[cnk&1]
            {
                const unsigned short* WB = (const unsigned short*)(smem + WO_OFF + (cnk & 1) * 32768);
                const int cH = cnk * 4 + ksl;          // 0..15 within half
                bf16x8 af2[4], bf2[4];
#pragma unroll
                for (int ai = 0; ai < 4; ai++) {
                    int rowH = (ai * 2 + ((lane >> 3) & 1)) * 16 + cH;
                    int okey = ((rowH >> 5) ^ (rowH >> 2)) & 7;
                    int chk  = (((lane & 7) * 4 + lg) ^ okey);
                    af2[ai] = *(const bf16x8*)&Oh[rowH * 256 + chk * 8];
                }
#pragma unroll
                for (int bi = 0; bi < 4; bi++) {
                    int z = zsl * 64 + bi * 16 + lr;
                    int chk = (ksl * 4 + lg) ^ (z & 15);
                    bf2[bi] = *(const bf16x8*)&WB[z * 128 + chk * 8];
                }
#pragma unroll
                for (int ai = 0; ai < 4; ai++)
#pragma unroll
                    for (int bi = 0; bi < 4; bi++)
                        acc2[ai][bi] = __builtin_amdgcn_mfma_f32_16x16x32_bf16(af2[ai], bf2[bi], acc2[ai][bi], 0, 0, 0);
            }
            // write prefetched chunk to other buffer
            if (cnk < 3) {
                unsigned short* WD = (unsigned short*)(smem + WO_OFF + ((cnk + 1) & 1) * 32768);
#pragma unroll
                for (int q = 0; q < 4; q++) {
                    int lam = q * 512 + t;
                    *(us8*)&WD[lam * 8] = wreg[q];
                }
            }
            __syncthreads();
        }
    }

    // ---- K-slot reduction: buf[4 ks][128 z][68 pair-stride] f32 ----
    float* RB = (float*)smem;
#pragma unroll
    for (int ai = 0; ai < 4; ai++)
#pragma unroll
        for (int bi = 0; bi < 4; bi++) {
            int z  = zsl * 64 + bi * 16 + lr;
            int pr = ai * 16 + lg * 4;
            *(f32x4*)&RB[ksl * 8704 + z * 68 + pr] = acc2[ai][bi];
        }
    __syncthreads();

    {
        int z = t >> 2, pq = t & 3;
        float bz = bo[z];
#pragma unroll
        for (int u = 0; u < 4; u++) {
            int p0r = pq * 16 + u * 4;
            f32x4 s = (f32x4){0.f, 0.f, 0.f, 0.f};
#pragma unroll
            for (int ks2 = 0; ks2 < 4; ks2++)
                s += *(const f32x4*)&RB[ks2 * 8704 + z * 68 + p0r];
#pragma unroll
            for (int e = 0; e < 4; e++) {
                int p = p0r + e;
                out[((size_t)(i0 + (p >> 3)) * NN + (j0 + (p & 7))) * CZ + z] = s[e] + bz;
            }
        }
    }
}

extern "C" void kernel_launch(void* const* d_in, const int* in_sizes, int n_in,
                              void* d_out, int out_size, void* d_ws, size_t ws_size,
                              hipStream_t stream) {
    const float* msa  = (const float*)d_in[0];
    const float* ln_g = (const float*)d_in[1];
    const float* ln_b = (const float*)d_in[2];
    const float* Wl   = (const float*)d_in[3];
    const float* bl   = (const float*)d_in[4];
    const float* Wr   = (const float*)d_in[5];
    const float* br   = (const float*)d_in[6];
    const float* Wo   = (const float*)d_in[7];
    const float* bo   = (const float*)d_in[8];
    float* out = (float*)d_out;

    unsigned short* Lt  = (unsigned short*)d_ws;                 // [12288][128] bf16
    unsigned short* Rt  = Lt + (size_t)NN * CH * SS;             // [12288][128] bf16
    unsigned short* WoT = Rt + (size_t)NN * CH * SS;             // [128][1024] bf16

    hipFuncSetAttribute((const void*)k1_ln_proj,
                        hipFuncAttributeMaxDynamicSharedMemorySize, K1_LDS);
    hipFuncSetAttribute((const void*)k2_fused,
                        hipFuncAttributeMaxDynamicSharedMemorySize, K2_LDS);

    k0_wo_t<<<dim3(CZ), dim3(256), 0, stream>>>(Wo, WoT);
    k1_ln_proj<<<dim3(NN), dim3(512), K1_LDS, stream>>>(msa, ln_g, ln_b, Wl, bl, Wr, br, Lt, Rt);
    k2_fused<<<dim3(NN / TI, NN / TJ), dim3(512), K2_LDS, stream>>>(Lt, Rt, WoT, bo, out);
}

// Round 4
// 248.818 us; speedup vs baseline: 1.3721x; 1.3721x over previous
//
#include <hip/hip_runtime.h>
#include <hip/hip_bf16.h>

#define CM 256
#define CZ 128
#define CH 32
#define SS 128
#define NN 384

typedef short bf16x8 __attribute__((ext_vector_type(8)));
typedef float f32x4 __attribute__((ext_vector_type(4)));
typedef unsigned short us4 __attribute__((ext_vector_type(4)));
typedef unsigned short us8 __attribute__((ext_vector_type(8)));

__device__ __forceinline__ unsigned short f2bf(float f) {
    __hip_bfloat16 h = __float2bfloat16(f);
    return __builtin_bit_cast(unsigned short, h);
}

// ---------------- K0: WoT[n][k] = bf16(Wo[k][n]) ----------------
__global__ void k0_wo_t(const float* __restrict__ Wo, unsigned short* __restrict__ WoT) {
    int n = blockIdx.x;  // 0..127
    for (int k = threadIdx.x; k < CH * CH; k += blockDim.x) {
        WoT[n * (CH * CH) + k] = f2bf(Wo[(size_t)k * CZ + n]);
    }
}

// ---------------- K1: LayerNorm + projections (block per i, full S) ----------------
// Lt[(i*32+c)][s] = (LN(msa) @ Wl + bl)[s,i,c] / 128 ; Rt[(i*32+d)][s] = (... @ Wr + br)
// K-dim here is CM=256 -> row stride 264 (256 + 8 pad). (R3's 136 was a buffer overrun.)
__global__ __launch_bounds__(512) void k1_ln_proj(
    const float* __restrict__ msa, const float* __restrict__ g, const float* __restrict__ bta,
    const float* __restrict__ Wl, const float* __restrict__ bl,
    const float* __restrict__ Wr, const float* __restrict__ br,
    unsigned short* __restrict__ Lt, unsigned short* __restrict__ Rt)
{
    __shared__ unsigned short A_lds[128 * 264];  // [s][k=0..255]
    __shared__ unsigned short B_lds[64 * 264];   // [n][k] (n<32: Wl col, else Wr col)

    const int i    = blockIdx.x;
    const int t    = threadIdx.x;
    const int wv   = t >> 6;
    const int lane = t & 63;
    const int lr   = lane & 15, lg = lane >> 4;

    // --- LN: wave w handles s = w*16 .. +16, lane covers 4 consecutive channels ---
    const float4 gv = ((const float4*)g)[lane];
    const float4 bv = ((const float4*)bta)[lane];
#pragma unroll 4
    for (int r = 0; r < 16; r++) {
        int s = wv * 16 + r;
        float4 v = ((const float4*)(msa + ((size_t)s * NN + i) * CM))[lane];
        float sum = v.x + v.y + v.z + v.w;
        float sq  = v.x * v.x + v.y * v.y + v.z * v.z + v.w * v.w;
#pragma unroll
        for (int off = 32; off >= 1; off >>= 1) {
            sum += __shfl_xor(sum, off, 64);
            sq  += __shfl_xor(sq, off, 64);
        }
        float mu = sum * (1.f / CM);
        float rs = rsqrtf(sq * (1.f / CM) - mu * mu + 1e-5f);
        us4 pk;
        pk[0] = f2bf((v.x - mu) * rs * gv.x + bv.x);
        pk[1] = f2bf((v.y - mu) * rs * gv.y + bv.y);
        pk[2] = f2bf((v.z - mu) * rs * gv.z + bv.z);
        pk[3] = f2bf((v.w - mu) * rs * gv.w + bv.w);
        *(us4*)&A_lds[s * 264 + lane * 4] = pk;
    }
    // --- W staging: B_lds[ch][k] (left), B_lds[32+ch][k] (right) ---
#pragma unroll 4
    for (int u = 0; u < 16; u++) {
        int e = u * 512 + t;          // e < 8192; e = k*32+ch
        int ch = e & 31, k = e >> 5;
        B_lds[ch * 264 + k]        = f2bf(Wl[e]);
        B_lds[(32 + ch) * 264 + k] = f2bf(Wr[e]);
    }
    __syncthreads();

    // --- MFMA: M=128(s) x N=64 x K=256; wave tile 32x32 ---
    const int m0 = (wv >> 1) * 32;
    const int n0 = (wv & 1) * 32;
    f32x4 acc[2][2];
#pragma unroll
    for (int a = 0; a < 2; a++)
#pragma unroll
        for (int b = 0; b < 2; b++) acc[a][b] = (f32x4){0.f, 0.f, 0.f, 0.f};

#pragma unroll
    for (int ks = 0; ks < 8; ks++) {
        int ko = ks * 32 + lg * 8;
        bf16x8 a0 = *(const bf16x8*)&A_lds[(m0 + lr) * 264 + ko];
        bf16x8 a1 = *(const bf16x8*)&A_lds[(m0 + 16 + lr) * 264 + ko];
        bf16x8 b0 = *(const bf16x8*)&B_lds[(n0 + lr) * 264 + ko];
        bf16x8 b1 = *(const bf16x8*)&B_lds[(n0 + 16 + lr) * 264 + ko];
        acc[0][0] = __builtin_amdgcn_mfma_f32_16x16x32_bf16(a0, b0, acc[0][0], 0, 0, 0);
        acc[0][1] = __builtin_amdgcn_mfma_f32_16x16x32_bf16(a0, b1, acc[0][1], 0, 0, 0);
        acc[1][0] = __builtin_amdgcn_mfma_f32_16x16x32_bf16(a1, b0, acc[1][0], 0, 0, 0);
        acc[1][1] = __builtin_amdgcn_mfma_f32_16x16x32_bf16(a1, b1, acc[1][1], 0, 0, 0);
    }

    // --- epilogue: C[m=s][n=ch] -> (Lt|Rt)[(i*32+ch)][s] ---
    const bool isL = (n0 == 0);   // wave-uniform
    const float scale = isL ? 0.0078125f : 1.f;   // 1/128 folded into left
#pragma unroll
    for (int mt = 0; mt < 2; mt++)
#pragma unroll
        for (int nt = 0; nt < 2; nt++) {
            int ch = (n0 + nt * 16 + lr) & 31;
            float bias = isL ? bl[ch] : br[ch];
            us4 pk;
#pragma unroll
            for (int rg = 0; rg < 4; rg++)
                pk[rg] = f2bf((acc[mt][nt][rg] + bias) * scale);
            unsigned short* dst = (isL ? Lt : Rt) + (size_t)(i * CH + ch) * SS + m0 + mt * 16 + lg * 4;
            *(us4*)dst = pk;
        }
}

// ---------------- K2: fused GEMM1 (outer) + GEMM2 (@Wo) ----------------
// LDS plan (163840 = 160 KiB exactly):
//   phase 1 : A [0,69632)  B [69632,139264)
//   phase 2 : Oh0 [0,65536)  Oh1 [65536,131072)  Wo chunk [131072,163840)
//   reduce  : RB f32 [0,139264)
#define TI 8
#define TJ 8
#define P1_B_OFF 69632     // 256*136*2
#define OH1_OFF  65536
#define WO_OFF   131072
#define K2_LDS   163840

__global__ __launch_bounds__(512, 2) void k2_fused(
    const unsigned short* __restrict__ Lt, const unsigned short* __restrict__ Rt,
    const unsigned short* __restrict__ WoT, const float* __restrict__ bo,
    float* __restrict__ out)
{
    extern __shared__ char smem[];
    unsigned short* A = (unsigned short*)(smem);             // [256][136]
    unsigned short* B = (unsigned short*)(smem + P1_B_OFF);  // [256][136]

    const int i0 = blockIdx.x * TI;
    const int j0 = blockIdx.y * TJ;
    const int t  = threadIdx.x;
    const int wv = t >> 6, lane = t & 63;
    const int lr = lane & 15, lg = lane >> 4;

    // ---- Phase 1 staging ----
    const unsigned short* gA = Lt + (size_t)i0 * CH * SS;
    const unsigned short* gB = Rt + (size_t)j0 * CH * SS;
#pragma unroll
    for (int it = 0; it < 8; it++) {
        int c  = it * 512 + t;
        int rw = c >> 4, kc = c & 15;
        *(us8*)(A + rw * 136 + kc * 8) = *(const us8*)(gA + rw * 128 + kc * 8);
        *(us8*)(B + rw * 136 + kc * 8) = *(const us8*)(gB + rw * 128 + kc * 8);
    }
    __syncthreads();

    // ---- Phase 1 compute: 256x256x128, wave tile 128x64 ----
    const int m0 = (wv >> 2) * 128;
    const int n0w = (wv & 3) * 64;

    f32x4 accE[4][4], accO[4][4];   // even/odd m-frag split (c-halves of O)
#pragma unroll
    for (int a = 0; a < 4; a++)
#pragma unroll
        for (int b = 0; b < 4; b++) {
            accE[a][b] = (f32x4){0.f, 0.f, 0.f, 0.f};
            accO[a][b] = (f32x4){0.f, 0.f, 0.f, 0.f};
        }

#pragma unroll
    for (int ks = 0; ks < 4; ks++) {
        int ko = ks * 32 + lg * 8;
        bf16x8 af[8], bfr[4];
#pragma unroll
        for (int mt = 0; mt < 8; mt++) af[mt]  = *(const bf16x8*)(A + (m0 + mt * 16 + lr) * 136 + ko);
#pragma unroll
        for (int nt = 0; nt < 4; nt++) bfr[nt] = *(const bf16x8*)(B + (n0w + nt * 16 + lr) * 136 + ko);
#pragma unroll
        for (int mt = 0; mt < 8; mt++)
#pragma unroll
            for (int nt = 0; nt < 4; nt++) {
                if (mt & 1)
                    accO[mt >> 1][nt] = __builtin_amdgcn_mfma_f32_16x16x32_bf16(af[mt], bfr[nt], accO[mt >> 1][nt], 0, 0, 0);
                else
                    accE[mt >> 1][nt] = __builtin_amdgcn_mfma_f32_16x16x32_bf16(af[mt], bfr[nt], accE[mt >> 1][nt], 0, 0, 0);
            }
    }
    __syncthreads();   // A/B reads complete; LDS repurposed

    // ---- Dump BOTH O halves (accs die here -> no spill pressure in phase 2) ----
    // Oh[h][rowH=iiw*16+clo][col=jj*32+d], XOR-swizzled; h = high bit of c (c = h*16+clo)
    {
        unsigned short* Oh0 = (unsigned short*)smem;
        unsigned short* Oh1 = (unsigned short*)(smem + OH1_OFF);
#pragma unroll
        for (int mh = 0; mh < 4; mh++) {
            int iiw = (wv >> 2) * 4 + mh;
#pragma unroll
            for (int nt = 0; nt < 4; nt++)
#pragma unroll
                for (int rg = 0; rg < 4; rg++) {
                    int rowH = iiw * 16 + lg * 4 + rg;
                    int col  = n0w + nt * 16 + lr;
                    int okey = ((rowH >> 5) ^ (rowH >> 2)) & 7;
                    int chk  = (col >> 3) ^ okey;
                    Oh0[rowH * 256 + chk * 8 + (col & 7)] = f2bf(accE[mh][nt][rg]);
                    Oh1[rowH * 256 + chk * 8 + (col & 7)] = f2bf(accO[mh][nt][rg]);
                }
        }
    }

    // ---- Phase 2: out[pair=64][z=128] = O[64][1024] @ WoT^T ----
    // 8 chunks of K=128; single-buffered 32KB Wo chunk; waves: zsl (2) x ksl (4)
    const int zsl = wv & 1, ksl = wv >> 1;
    unsigned short* WB = (unsigned short*)(smem + WO_OFF);

    f32x4 acc2[4][4];
#pragma unroll
    for (int a = 0; a < 4; a++)
#pragma unroll
        for (int b = 0; b < 4; b++) acc2[a][b] = (f32x4){0.f, 0.f, 0.f, 0.f};

    for (int c = 0; c < 8; c++) {
        __syncthreads();   // O dump done (c==0) / previous chunk reads done
        {
#pragma unroll
            for (int q = 0; q < 4; q++) {
                int lam = q * 512 + t;
                int z = lam >> 4, cc = lam & 15;
                int cg = cc ^ (z & 15);
                *(us8*)&WB[lam * 8] = *(const us8*)&WoT[(size_t)z * 1024 + c * 128 + cg * 8];
            }
        }
        __syncthreads();

        const int cch = c * 4 + ksl;           // 0..31
        const int hh  = cch >> 4;
        const int cH  = cch & 15;
        const unsigned short* OhX = (const unsigned short*)(smem + (hh ? OH1_OFF : 0));

        bf16x8 af2[4], bf2[4];
#pragma unroll
        for (int ai = 0; ai < 4; ai++) {
            int rowH = (ai * 2 + ((lane >> 3) & 1)) * 16 + cH;
            int okey = ((rowH >> 5) ^ (rowH >> 2)) & 7;
            int chk  = (((lane & 7) * 4 + lg) ^ okey);
            af2[ai] = *(const bf16x8*)&OhX[rowH * 256 + chk * 8];
        }
#pragma unroll
        for (int bi = 0; bi < 4; bi++) {
            int z = zsl * 64 + bi * 16 + lr;
            int chk = (ksl * 4 + lg) ^ (z & 15);
            bf2[bi] = *(const bf16x8*)&WB[z * 128 + chk * 8];
        }
#pragma unroll
        for (int ai = 0; ai < 4; ai++)
#pragma unroll
            for (int bi = 0; bi < 4; bi++)
                acc2[ai][bi] = __builtin_amdgcn_mfma_f32_16x16x32_bf16(af2[ai], bf2[bi], acc2[ai][bi], 0, 0, 0);
    }
    __syncthreads();   // O/WB reads done; LDS -> reduction buffer

    // ---- K-slot reduction: RB[4 ks][128 z][68 pair-stride] f32 ----
    float* RB = (float*)smem;
#pragma unroll
    for (int ai = 0; ai < 4; ai++)
#pragma unroll
        for (int bi = 0; bi < 4; bi++) {
            int z  = zsl * 64 + bi * 16 + lr;
            int pr = ai * 16 + lg * 4;
            *(f32x4*)&RB[ksl * 8704 + z * 68 + pr] = acc2[ai][bi];
        }
    __syncthreads();

    {
        int z = t >> 2, pq = t & 3;
        float bz = bo[z];
#pragma unroll
        for (int u = 0; u < 4; u++) {
            int p0r = pq * 16 + u * 4;
            f32x4 s = (f32x4){0.f, 0.f, 0.f, 0.f};
#pragma unroll
            for (int ks2 = 0; ks2 < 4; ks2++)
                s += *(const f32x4*)&RB[ks2 * 8704 + z * 68 + p0r];
#pragma unroll
            for (int e = 0; e < 4; e++) {
                int p = p0r + e;
                out[((size_t)(i0 + (p >> 3)) * NN + (j0 + (p & 7))) * CZ + z] = s[e] + bz;
            }
        }
    }
}

extern "C" void kernel_launch(void* const* d_in, const int* in_sizes, int n_in,
                              void* d_out, int out_size, void* d_ws, size_t ws_size,
                              hipStream_t stream) {
    const float* msa  = (const float*)d_in[0];
    const float* ln_g = (const float*)d_in[1];
    const float* ln_b = (const float*)d_in[2];
    const float* Wl   = (const float*)d_in[3];
    const float* bl   = (const float*)d_in[4];
    const float* Wr   = (const float*)d_in[5];
    const float* br   = (const float*)d_in[6];
    const float* Wo   = (const float*)d_in[7];
    const float* bo   = (const float*)d_in[8];
    float* out = (float*)d_out;

    unsigned short* Lt  = (unsigned short*)d_ws;                 // [12288][128] bf16
    unsigned short* Rt  = Lt + (size_t)NN * CH * SS;             // [12288][128] bf16
    unsigned short* WoT = Rt + (size_t)NN * CH * SS;             // [128][1024] bf16

    hipFuncSetAttribute((const void*)k2_fused,
                        hipFuncAttributeMaxDynamicSharedMemorySize, K2_LDS);

    k0_wo_t<<<dim3(CZ), dim3(256), 0, stream>>>(Wo, WoT);
    k1_ln_proj<<<dim3(NN), dim3(512), 0, stream>>>(msa, ln_g, ln_b, Wl, bl, Wr, br, Lt, Rt);
    k2_fused<<<dim3(NN / TI, NN / TJ), dim3(512), K2_LDS, stream>>>(Lt, Rt, WoT, bo, out);
}

// Round 5
// 221.630 us; speedup vs baseline: 1.5405x; 1.1227x over previous
//
#include <hip/hip_runtime.h>
#include <hip/hip_bf16.h>

#define CM 256
#define CZ 128
#define CH 32
#define SS 128
#define NN 384

typedef short bf16x8 __attribute__((ext_vector_type(8)));
typedef float f32x4 __attribute__((ext_vector_type(4)));
typedef unsigned short us4 __attribute__((ext_vector_type(4)));
typedef unsigned short us8 __attribute__((ext_vector_type(8)));

__device__ __forceinline__ unsigned short f2bf(float f) {
    __hip_bfloat16 h = __float2bfloat16(f);
    return __builtin_bit_cast(unsigned short, h);
}

// ---------------- K0: transposes. WoT[n][k]=Wo[k][n]; WT = [WlT(32x256) | WrT(32x256)] ----------------
__global__ __launch_bounds__(256) void k0_transpose(
    const float* __restrict__ Wo, const float* __restrict__ Wl, const float* __restrict__ Wr,
    unsigned short* __restrict__ WoT, unsigned short* __restrict__ WT) {
    int n = blockIdx.x;  // 0..127
    for (int k = threadIdx.x; k < CH * CH; k += blockDim.x) {
        WoT[n * (CH * CH) + k] = f2bf(Wo[(size_t)k * CZ + n]);
    }
    int k = threadIdx.x;  // blockDim == 256 == CM
    if (n < 32) {
        WT[n * CM + k] = f2bf(Wl[(size_t)k * CH + n]);
    } else if (n < 64) {
        WT[32 * CM + (n - 32) * CM + k] = f2bf(Wr[(size_t)k * CH + (n - 32)]);
    }
}

// ---------------- K1: LayerNorm + projections. Block = (i, s-half of 64). 256 thr, 2 blocks/CU ----------------
// Lt[(i*32+c)][s] = (LN(msa) @ Wl + bl)[s,i,c] / 128 ; Rt[(i*32+d)][s] = (... @ Wr + br)
__global__ __launch_bounds__(256, 2) void k1_ln_proj(
    const float* __restrict__ msa, const float* __restrict__ g, const float* __restrict__ bta,
    const unsigned short* __restrict__ WT, const float* __restrict__ bl, const float* __restrict__ br,
    unsigned short* __restrict__ Lt, unsigned short* __restrict__ Rt)
{
    __shared__ unsigned short A_lds[64 * 264];  // [s-local][k=0..255], +8 pad
    __shared__ unsigned short B_lds[64 * 264];  // [n][k] (n<32: Wl col, else Wr col)

    const int i    = blockIdx.x;
    const int sh   = blockIdx.y;        // s-half: 0 or 1
    const int t    = threadIdx.x;
    const int wv   = t >> 6;            // 0..3
    const int lane = t & 63;
    const int lr   = lane & 15, lg = lane >> 4;

    // --- LN: wave w handles local rows w*16..+15; lane covers 4 consecutive channels ---
    const float4 gv = ((const float4*)g)[lane];
    const float4 bv = ((const float4*)bta)[lane];
#pragma unroll 4
    for (int r = 0; r < 16; r++) {
        int sl = wv * 16 + r;
        int s  = sh * 64 + sl;
        float4 v = ((const float4*)(msa + ((size_t)s * NN + i) * CM))[lane];
        float sum = v.x + v.y + v.z + v.w;
        float sq  = v.x * v.x + v.y * v.y + v.z * v.z + v.w * v.w;
#pragma unroll
        for (int off = 32; off >= 1; off >>= 1) {
            sum += __shfl_xor(sum, off, 64);
            sq  += __shfl_xor(sq, off, 64);
        }
        float mu = sum * (1.f / CM);
        float rs = rsqrtf(sq * (1.f / CM) - mu * mu + 1e-5f);
        us4 pk;
        pk[0] = f2bf((v.x - mu) * rs * gv.x + bv.x);
        pk[1] = f2bf((v.y - mu) * rs * gv.y + bv.y);
        pk[2] = f2bf((v.z - mu) * rs * gv.z + bv.z);
        pk[3] = f2bf((v.w - mu) * rs * gv.w + bv.w);
        *(us4*)&A_lds[sl * 264 + lane * 4] = pk;
    }
    // --- W staging: pure us8 copies from pre-transposed WT ---
#pragma unroll
    for (int u = 0; u < 8; u++) {
        int id = u * 256 + t;            // 0..2047 us8 chunks; row = id>>5, kc = id&31
        *(us8*)&B_lds[(id >> 5) * 264 + (id & 31) * 8] = *(const us8*)&WT[id * 8];
    }
    __syncthreads();

    // --- MFMA: M=64(s) x N=64 x K=256; wave tile 32x32 ---
    const int m0 = (wv >> 1) * 32;
    const int n0 = (wv & 1) * 32;
    f32x4 acc[2][2];
#pragma unroll
    for (int a = 0; a < 2; a++)
#pragma unroll
        for (int b = 0; b < 2; b++) acc[a][b] = (f32x4){0.f, 0.f, 0.f, 0.f};

#pragma unroll
    for (int ks = 0; ks < 8; ks++) {
        int ko = ks * 32 + lg * 8;
        bf16x8 a0 = *(const bf16x8*)&A_lds[(m0 + lr) * 264 + ko];
        bf16x8 a1 = *(const bf16x8*)&A_lds[(m0 + 16 + lr) * 264 + ko];
        bf16x8 b0 = *(const bf16x8*)&B_lds[(n0 + lr) * 264 + ko];
        bf16x8 b1 = *(const bf16x8*)&B_lds[(n0 + 16 + lr) * 264 + ko];
        acc[0][0] = __builtin_amdgcn_mfma_f32_16x16x32_bf16(a0, b0, acc[0][0], 0, 0, 0);
        acc[0][1] = __builtin_amdgcn_mfma_f32_16x16x32_bf16(a0, b1, acc[0][1], 0, 0, 0);
        acc[1][0] = __builtin_amdgcn_mfma_f32_16x16x32_bf16(a1, b0, acc[1][0], 0, 0, 0);
        acc[1][1] = __builtin_amdgcn_mfma_f32_16x16x32_bf16(a1, b1, acc[1][1], 0, 0, 0);
    }

    // --- epilogue: C[m=s][n=ch] -> (Lt|Rt)[(i*32+ch)][s] ---
    const bool isL = (n0 == 0);   // wave-uniform
    const float scale = isL ? 0.0078125f : 1.f;   // 1/128 folded into left
#pragma unroll
    for (int mt = 0; mt < 2; mt++)
#pragma unroll
        for (int nt = 0; nt < 2; nt++) {
            int ch = (n0 + nt * 16 + lr) & 31;
            float bias = isL ? bl[ch] : br[ch];
            us4 pk;
#pragma unroll
            for (int rg = 0; rg < 4; rg++)
                pk[rg] = f2bf((acc[mt][nt][rg] + bias) * scale);
            unsigned short* dst = (isL ? Lt : Rt) + (size_t)(i * CH + ch) * SS
                                  + sh * 64 + m0 + mt * 16 + lg * 4;
            *(us4*)dst = pk;
        }
}

// ---------------- K2: fused GEMM1 (outer) + GEMM2 (@Wo) ----------------
// LDS plan (163840 = 160 KiB exactly):
//   phase 1 : A [0,69632)  B [69632,139264)
//   phase 2 : Oh0 [0,65536)  Oh1 [65536,131072)  Wo chunk [131072,163840)
//   reduce  : RB f32 [0,139264)
#define TI 8
#define TJ 8
#define P1_B_OFF 69632     // 256*136*2
#define OH1_OFF  65536
#define WO_OFF   131072
#define K2_LDS   163840

__global__ __launch_bounds__(512, 2) void k2_fused(
    const unsigned short* __restrict__ Lt, const unsigned short* __restrict__ Rt,
    const unsigned short* __restrict__ WoT, const float* __restrict__ bo,
    float* __restrict__ out)
{
    extern __shared__ char smem[];
    unsigned short* A = (unsigned short*)(smem);             // [256][136]
    unsigned short* B = (unsigned short*)(smem + P1_B_OFF);  // [256][136]

    const int i0 = blockIdx.x * TI;
    const int j0 = blockIdx.y * TJ;
    const int t  = threadIdx.x;
    const int wv = t >> 6, lane = t & 63;
    const int lr = lane & 15, lg = lane >> 4;

    // ---- Phase 1 staging ----
    const unsigned short* gA = Lt + (size_t)i0 * CH * SS;
    const unsigned short* gB = Rt + (size_t)j0 * CH * SS;
#pragma unroll
    for (int it = 0; it < 8; it++) {
        int c  = it * 512 + t;
        int rw = c >> 4, kc = c & 15;
        *(us8*)(A + rw * 136 + kc * 8) = *(const us8*)(gA + rw * 128 + kc * 8);
        *(us8*)(B + rw * 136 + kc * 8) = *(const us8*)(gB + rw * 128 + kc * 8);
    }
    __syncthreads();

    // ---- Phase 1 compute: 256x256x128, wave tile 128x64, OPERANDS SWAPPED ----
    // acc element (lane,rg): O[rowA = m0+mt*16+lr][colB = n0w+nt*16+lg*4+rg]
    const int m0  = (wv >> 2) * 128;
    const int n0w = (wv & 3) * 64;

    f32x4 accE[4][4], accO[4][4];   // mt even (h=0) / mt odd (h=1)
#pragma unroll
    for (int a = 0; a < 4; a++)
#pragma unroll
        for (int b = 0; b < 4; b++) {
            accE[a][b] = (f32x4){0.f, 0.f, 0.f, 0.f};
            accO[a][b] = (f32x4){0.f, 0.f, 0.f, 0.f};
        }

#pragma unroll
    for (int ks = 0; ks < 4; ks++) {
        int ko = ks * 32 + lg * 8;
        bf16x8 af[8], bfr[4];
#pragma unroll
        for (int mt = 0; mt < 8; mt++) af[mt]  = *(const bf16x8*)(A + (m0 + mt * 16 + lr) * 136 + ko);
#pragma unroll
        for (int nt = 0; nt < 4; nt++) bfr[nt] = *(const bf16x8*)(B + (n0w + nt * 16 + lr) * 136 + ko);
#pragma unroll
        for (int mt = 0; mt < 8; mt++)
#pragma unroll
            for (int nt = 0; nt < 4; nt++) {
                if (mt & 1)
                    accO[mt >> 1][nt] = __builtin_amdgcn_mfma_f32_16x16x32_bf16(bfr[nt], af[mt], accO[mt >> 1][nt], 0, 0, 0);
                else
                    accE[mt >> 1][nt] = __builtin_amdgcn_mfma_f32_16x16x32_bf16(bfr[nt], af[mt], accE[mt >> 1][nt], 0, 0, 0);
            }
    }
    __syncthreads();   // A/B reads complete; LDS repurposed

    // ---- Prefetch Wo chunk 0 into regs (latency hidden behind O dump) ----
    us8 wreg[4];
#pragma unroll
    for (int q = 0; q < 4; q++) {
        int lam = q * 512 + t;
        int z = lam >> 4, cc = lam & 15;
        int cg = cc ^ (z & 15);
        wreg[q] = *(const us8*)&WoT[(size_t)z * 1024 + cg * 8];
    }

    // ---- Dump BOTH O halves with b64 packed writes ----
    // Oh[h][rowH=ii*16+lr][col], okey = (rowH ^ (rowH>>4)) & 7, chk = (col>>3)^okey
    {
        unsigned short* Oh0 = (unsigned short*)smem;
        unsigned short* Oh1 = (unsigned short*)(smem + OH1_OFF);
#pragma unroll
        for (int mh = 0; mh < 4; mh++) {
            int iiw  = (wv >> 2) * 4 + mh;
            int rowH = iiw * 16 + lr;
            int okey = (rowH ^ (rowH >> 4)) & 7;
#pragma unroll
            for (int nt = 0; nt < 4; nt++) {
                int colBase = n0w + nt * 16 + lg * 4;     // + rg (0..3), no octet carry
                int chk = (colBase >> 3) ^ okey;
                int off = rowH * 256 + chk * 8 + (lg & 1) * 4;
                us4 pkE, pkO;
#pragma unroll
                for (int rg = 0; rg < 4; rg++) {
                    pkE[rg] = f2bf(accE[mh][nt][rg]);
                    pkO[rg] = f2bf(accO[mh][nt][rg]);
                }
                *(us4*)&Oh0[off] = pkE;
                *(us4*)&Oh1[off] = pkO;
            }
        }
    }

    // ---- Phase 2: out[pair=64][z=128] = O[64][1024] @ WoT^T ----
    // 8 chunks of K=128; single 32KB WB, register double-buffer; waves: zsl(2) x ksl(4)
    const int zsl = wv & 1, ksl = wv >> 1;
    unsigned short* WB = (unsigned short*)(smem + WO_OFF);

    f32x4 acc2[4][4];
#pragma unroll
    for (int a = 0; a < 4; a++)
#pragma unroll
        for (int b = 0; b < 4; b++) acc2[a][b] = (f32x4){0.f, 0.f, 0.f, 0.f};

    for (int c = 0; c < 8; c++) {
        __syncthreads();   // O dump done (c==0) / previous chunk reads done
#pragma unroll
        for (int q = 0; q < 4; q++) {
            int lam = q * 512 + t;
            *(us8*)&WB[lam * 8] = wreg[q];
        }
        if (c < 7) {       // prefetch next chunk; vmcnt waits overlap MFMA below
#pragma unroll
            for (int q = 0; q < 4; q++) {
                int lam = q * 512 + t;
                int z = lam >> 4, cc = lam & 15;
                int cg = cc ^ (z & 15);
                wreg[q] = *(const us8*)&WoT[(size_t)z * 1024 + (c + 1) * 128 + cg * 8];
            }
        }
        __syncthreads();

        const int cch = c * 4 + ksl;           // 0..31
        const int hh  = cch >> 4;
        const int cH  = cch & 15;
        const unsigned short* OhX = (const unsigned short*)(smem + (hh ? OH1_OFF : 0));

        bf16x8 af2[4], bf2[4];
#pragma unroll
        for (int ai = 0; ai < 4; ai++) {
            int rowH = (ai * 2 + ((lane >> 3) & 1)) * 16 + cH;
            int okey = (rowH ^ (rowH >> 4)) & 7;
            int chk  = (((lane & 7) * 4 + lg) ^ okey);
            af2[ai] = *(const bf16x8*)&OhX[rowH * 256 + chk * 8];
        }
#pragma unroll
        for (int bi = 0; bi < 4; bi++) {
            int z = zsl * 64 + bi * 16 + lr;
            int chk = (ksl * 4 + lg) ^ (z & 15);
            bf2[bi] = *(const bf16x8*)&WB[z * 128 + chk * 8];
        }
#pragma unroll
        for (int ai = 0; ai < 4; ai++)
#pragma unroll
            for (int bi = 0; bi < 4; bi++)
                acc2[ai][bi] = __builtin_amdgcn_mfma_f32_16x16x32_bf16(af2[ai], bf2[bi], acc2[ai][bi], 0, 0, 0);
    }
    __syncthreads();   // O/WB reads done; LDS -> reduction buffer

    // ---- K-slot reduction: RB[4 ks][128 z][68 pair-stride] f32 ----
    float* RB = (float*)smem;
#pragma unroll
    for (int ai = 0; ai < 4; ai++)
#pragma unroll
        for (int bi = 0; bi < 4; bi++) {
            int z  = zsl * 64 + bi * 16 + lr;
            int pr = ai * 16 + lg * 4;
            *(f32x4*)&RB[ksl * 8704 + z * 68 + pr] = acc2[ai][bi];
        }
    __syncthreads();

    {
        int z = t >> 2, pq = t & 3;
        float bz = bo[z];
#pragma unroll
        for (int u = 0; u < 4; u++) {
            int p0r = pq * 16 + u * 4;
            f32x4 s = (f32x4){0.f, 0.f, 0.f, 0.f};
#pragma unroll
            for (int ks2 = 0; ks2 < 4; ks2++)
                s += *(const f32x4*)&RB[ks2 * 8704 + z * 68 + p0r];
#pragma unroll
            for (int e = 0; e < 4; e++) {
                int p = p0r + e;
                out[((size_t)(i0 + (p >> 3)) * NN + (j0 + (p & 7))) * CZ + z] = s[e] + bz;
            }
        }
    }
}

extern "C" void kernel_launch(void* const* d_in, const int* in_sizes, int n_in,
                              void* d_out, int out_size, void* d_ws, size_t ws_size,
                              hipStream_t stream) {
    const float* msa  = (const float*)d_in[0];
    const float* ln_g = (const float*)d_in[1];
    const float* ln_b = (const float*)d_in[2];
    const float* Wl   = (const float*)d_in[3];
    const float* bl   = (const float*)d_in[4];
    const float* Wr   = (const float*)d_in[5];
    const float* br   = (const float*)d_in[6];
    const float* Wo   = (const float*)d_in[7];
    const float* bo   = (const float*)d_in[8];
    float* out = (float*)d_out;

    unsigned short* Lt  = (unsigned short*)d_ws;                 // [12288][128] bf16
    unsigned short* Rt  = Lt + (size_t)NN * CH * SS;             // [12288][128] bf16
    unsigned short* WoT = Rt + (size_t)NN * CH * SS;             // [128][1024] bf16
    unsigned short* WT  = WoT + (size_t)CZ * CH * CH;            // [64][256] bf16 (WlT|WrT)

    hipFuncSetAttribute((const void*)k2_fused,
                        hipFuncAttributeMaxDynamicSharedMemorySize, K2_LDS);

    k0_transpose<<<dim3(CZ), dim3(256), 0, stream>>>(Wo, Wl, Wr, WoT, WT);
    k1_ln_proj<<<dim3(NN, 2), dim3(256), 0, stream>>>(msa, ln_g, ln_b, WT, bl, br, Lt, Rt);
    k2_fused<<<dim3(NN / TI, NN / TJ), dim3(512), K2_LDS, stream>>>(Lt, Rt, WoT, bo, out);
}